// Round 8
// baseline (722.528 us; speedup 1.0000x reference)
//
#include <hip/hip_runtime.h>
#include <hip/hip_bf16.h>
#include <math.h>

typedef __hip_bfloat16 bf16;
typedef __attribute__((ext_vector_type(8))) short short8;
typedef __attribute__((ext_vector_type(4))) float f32x4;

#define EPSV 0.0001f

__device__ __forceinline__ unsigned short f2bf(float f) {  // RNE bf16 bits
    unsigned int u = __float_as_uint(f);
    u += 0x7fff + ((u >> 16) & 1);
    return (unsigned short)(u >> 16);
}

// ---------------------------------------------------------------------------
// Kernel 1: weight row-norm + cast to bf16 with scale folded in.
// ---------------------------------------------------------------------------
__global__ __launch_bounds__(256) void rownorm_cast_kernel(
    const float* __restrict__ w_qkv, const float* __restrict__ w_proj,
    unsigned short* __restrict__ Wqb, unsigned short* __restrict__ Wpb)
{
    const int row = blockIdx.x;
    const float* src;
    unsigned short* dst;
    if (row < 2304) { src = w_qkv + (size_t)row * 768;           dst = Wqb + (size_t)row * 768; }
    else            { src = w_proj + (size_t)(row - 2304) * 768; dst = Wpb + (size_t)(row - 2304) * 768; }

    const int tid = threadIdx.x;
    float v[3];
    float ss = 0.f;
    #pragma unroll
    for (int j = 0; j < 3; j++) {
        v[j] = src[tid + j * 256];
        ss += v[j] * v[j];
    }
    #pragma unroll
    for (int off = 32; off > 0; off >>= 1) ss += __shfl_down(ss, off, 64);
    __shared__ float wsum[4];
    if ((tid & 63) == 0) wsum[tid >> 6] = ss;
    __syncthreads();
    const float total = wsum[0] + wsum[1] + wsum[2] + wsum[3];
    const float scale = 1.0f / (EPSV * 27.712812921102035f + sqrtf(total)); // sqrt(768)
    #pragma unroll
    for (int j = 0; j < 3; j++) dst[tid + j * 256] = f2bf(v[j] * scale);
}

// ---------------------------------------------------------------------------
// Kernel 2: X [32][768][256] fp32 -> XbT [32][256][768] bf16 (transposed).
// ---------------------------------------------------------------------------
__global__ __launch_bounds__(256) void cast_x_kernel(
    const float* __restrict__ X, unsigned short* __restrict__ XbT)
{
    const int c0 = blockIdx.x * 64;
    const int b  = blockIdx.y;
    const int pos = threadIdx.x;
    const float* src = X + ((size_t)b * 768 + c0) * 256 + pos;
    unsigned short* dst = XbT + ((size_t)b * 256 + pos) * 768 + c0;
    #pragma unroll
    for (int cc = 0; cc < 8; cc++) {
        short8 t;
        #pragma unroll
        for (int j = 0; j < 8; j++)
            t[j] = (short)f2bf(src[(size_t)(cc * 8 + j) * 256]);
        *(short8*)&dst[cc * 8] = t;
    }
}

// ---------------------------------------------------------------------------
// Kernel 3: QKV GEMM (MFMA bf16), wide tile (round-6 structure).
// ---------------------------------------------------------------------------
__global__ __launch_bounds__(256, 2) void qkv_mfma_kernel(
    const unsigned short* __restrict__ Wqb,  // [2304][768] bf16, scale folded
    const unsigned short* __restrict__ XbT,  // [32][256][768] bf16
    bf16* __restrict__ Q, bf16* __restrict__ K, bf16* __restrict__ Vt)
{
    const int g = blockIdx.x;            // 0..35 (= qkv*12 + head)
    const int b = blockIdx.y;            // 0..31 (= bs*16 + fr)
    const int bs = b >> 4, fr = b & 15;
    const int qkv = g / 12, head = g % 12;
    const int m0 = g * 64;

    const int tid = threadIdx.x;
    const int w = tid >> 6, lane = tid & 63;
    const int l15 = lane & 15, quad = lane >> 4;

    __shared__ unsigned short As[64 * 72];
    __shared__ unsigned short Bs[256 * 72];

    const unsigned short* Ag = Wqb + (size_t)m0 * 768;
    const unsigned short* Bg = XbT + (size_t)b * 256 * 768;

    f32x4 acc[4][4];   // [mi][ni]
    #pragma unroll
    for (int mi = 0; mi < 4; mi++)
        #pragma unroll
        for (int ni = 0; ni < 4; ni++)
            acc[mi][ni] = (f32x4){0.f, 0.f, 0.f, 0.f};

    const int arow = tid >> 2, acol = (tid & 3) * 16;
    const int brow = tid >> 3, bcol = (tid & 7) * 8;

    for (int k0 = 0; k0 < 768; k0 += 64) {
        const short8 av0 = *(const short8*)&Ag[(size_t)arow * 768 + k0 + acol];
        const short8 av1 = *(const short8*)&Ag[(size_t)arow * 768 + k0 + acol + 8];
        short8 bv[8];
        #pragma unroll
        for (int p = 0; p < 8; p++)
            bv[p] = *(const short8*)&Bg[(size_t)(32 * p + brow) * 768 + k0 + bcol];
        __syncthreads();
        *(short8*)&As[arow * 72 + acol] = av0;
        *(short8*)&As[arow * 72 + acol + 8] = av1;
        #pragma unroll
        for (int p = 0; p < 8; p++)
            *(short8*)&Bs[(32 * p + brow) * 72 + bcol] = bv[p];
        __syncthreads();

        short8 af[4][2], bfr[4][2];
        #pragma unroll
        for (int mi = 0; mi < 4; mi++)
            #pragma unroll
            for (int kk = 0; kk < 2; kk++)
                af[mi][kk] = *(const short8*)&As[(16 * mi + l15) * 72 + 32 * kk + 8 * quad];
        #pragma unroll
        for (int ni = 0; ni < 4; ni++)
            #pragma unroll
            for (int kk = 0; kk < 2; kk++)
                bfr[ni][kk] = *(const short8*)&Bs[(64 * w + 16 * ni + l15) * 72 + 32 * kk + 8 * quad];
        #pragma unroll
        for (int kk = 0; kk < 2; kk++)
            #pragma unroll
            for (int mi = 0; mi < 4; mi++)
                #pragma unroll
                for (int ni = 0; ni < 4; ni++)
                    acc[mi][ni] = __builtin_amdgcn_mfma_f32_16x16x32_bf16(af[mi][kk], bfr[ni][kk], acc[mi][ni], 0, 0, 0);
    }

    float inv[4];
    #pragma unroll
    for (int ni = 0; ni < 4; ni++) {
        float ssq = 0.f;
        #pragma unroll
        for (int mi = 0; mi < 4; mi++)
            #pragma unroll
            for (int r = 0; r < 4; r++)
                ssq = fmaf(acc[mi][ni][r], acc[mi][ni][r], ssq);
        ssq += __shfl_xor(ssq, 16, 64);
        ssq += __shfl_xor(ssq, 32, 64);
        inv[ni] = 1.0f / (EPSV + sqrtf(ssq) * 0.125f);
    }

    if (qkv == 2) {
        unsigned short* Vb = &Bs[w * 64 * 72];
        #pragma unroll
        for (int ni = 0; ni < 4; ni++)
            #pragma unroll
            for (int mi = 0; mi < 4; mi++) {
                uint2 d;
                d.x = (unsigned int)f2bf(acc[mi][ni][0] * inv[ni]) |
                      ((unsigned int)f2bf(acc[mi][ni][1] * inv[ni]) << 16);
                d.y = (unsigned int)f2bf(acc[mi][ni][2] * inv[ni]) |
                      ((unsigned int)f2bf(acc[mi][ni][3] * inv[ni]) << 16);
                *(uint2*)&Vb[(16 * ni + l15) * 72 + 16 * mi + 4 * quad] = d;
            }
        unsigned short* Vtu = (unsigned short*)Vt;
        const size_t cb = ((size_t)(bs * 12 + head) * 64);
        const int tok = fr * 256 + 64 * w + lane;
        #pragma unroll 8
        for (int ch = 0; ch < 64; ch++)
            Vtu[(cb + ch) * 4096 + tok] = Vb[lane * 72 + ch];
    } else {
        unsigned short* dst = (unsigned short*)((qkv == 0) ? Q : K);
        const float post = (qkv == 0) ? 0.125f : 1.0f;   // fold 1/sqrt(c) into Q
        #pragma unroll
        for (int ni = 0; ni < 4; ni++) {
            const int token = fr * 256 + 64 * w + 16 * ni + l15;
            const size_t base = (((size_t)(bs * 12 + head)) * 4096 + token) * 64;
            #pragma unroll
            for (int mi = 0; mi < 2; mi++) {
                unsigned int lo[2], hi[2];
                #pragma unroll
                for (int r = 0; r < 4; r++) {
                    const int j = 16 * mi + 4 * quad + r;
                    const float n1 = acc[mi][ni][r] * inv[ni];
                    const float n2 = acc[mi + 2][ni][r] * inv[ni];
                    const float ang = (float)fr * exp2f(-(float)j * 0.41524101186092029f);
                    float sn, cs;
                    __sincosf(ang, &sn, &cs);
                    const unsigned short o1 = f2bf((n1 * cs - n2 * sn) * post);
                    const unsigned short o2 = f2bf((n2 * cs + n1 * sn) * post);
                    if (r < 2) { if (r == 0) { lo[0] = o1; hi[0] = o2; } else { lo[0] |= (unsigned int)o1 << 16; hi[0] |= (unsigned int)o2 << 16; } }
                    else       { if (r == 2) { lo[1] = o1; hi[1] = o2; } else { lo[1] |= (unsigned int)o1 << 16; hi[1] |= (unsigned int)o2 << 16; } }
                }
                *(uint2*)&dst[base + 16 * mi + 4 * quad]      = make_uint2(lo[0], lo[1]);
                *(uint2*)&dst[base + 32 + 16 * mi + 4 * quad] = make_uint2(hi[0], hi[1]);
            }
        }
    }
}

// ---------------------------------------------------------------------------
// Kernel 4: MFMA flash attention, frame-causal. BARRIER-FREE: K and V
// fragments load directly from global (L2) — A-op K[key][ch] rows and B-op
// Vt[ch][token] rows are natively 16 B/lane patterns. LDS only holds the
// per-wave P transpose buffer (same-wave write->read, lgkmcnt only).
// ---------------------------------------------------------------------------
__global__ __launch_bounds__(256, 4) void attn_mfma_kernel(
    const bf16* __restrict__ Qg, const bf16* __restrict__ Kg,
    const bf16* __restrict__ Vtg, unsigned short* __restrict__ OspT)
{
    const int qtile = 63 - blockIdx.x;           // heavy first
    const int qfr = qtile >> 2;
    const int head = blockIdx.y, bs = blockIdx.z;
    const int tid = threadIdx.x;
    const int w = tid >> 6, lane = tid & 63;
    const int l15 = lane & 15, quad = lane >> 4;
    const size_t hb = ((size_t)(bs * 12 + head)) * 4096 * 64;

    __shared__ unsigned short Pw[4][16 * 72];    // 9.2 KB total

    const unsigned short* Qu = (const unsigned short*)Qg;
    const unsigned short* Ku = (const unsigned short*)Kg;
    const unsigned short* Vu = (const unsigned short*)Vtg;

    // Q fragments (B operand of S^T)
    short8 Qf[2];
    {
        const int qrow = qfr * 256 + (qtile & 3) * 64 + w * 16 + l15;
        #pragma unroll
        for (int kk = 0; kk < 2; kk++)
            Qf[kk] = *(const short8*)&Qu[hb + (size_t)qrow * 64 + 32 * kk + 8 * quad];
    }

    f32x4 O[4];
    #pragma unroll
    for (int c = 0; c < 4; c++) O[c] = (f32x4){0.f, 0.f, 0.f, 0.f};
    float lsum = 0.f;
    const f32x4 zf = (f32x4){0.f, 0.f, 0.f, 0.f};

    // lane-fixed address parts
    const unsigned short* Kl = Ku + hb + (size_t)l15 * 64 + 8 * quad;     // + (t0+16mi)*64 (+32)
    const unsigned short* Vl = Vu + hb + (size_t)l15 * 4096 + 8 * quad;   // + ci*16*4096 + t0 (+32)

    const int nk = (qfr + 1) * 256;
    for (int t0 = 0; t0 < nk; t0 += 64) {
        // S^T = K · Q^T, K-fragments straight from global
        f32x4 St[4];
        #pragma unroll
        for (int mi = 0; mi < 4; mi++) {
            const short8 af0 = *(const short8*)&Kl[(size_t)(t0 + 16 * mi) * 64];
            const short8 af1 = *(const short8*)&Kl[(size_t)(t0 + 16 * mi) * 64 + 32];
            f32x4 s = __builtin_amdgcn_mfma_f32_16x16x32_bf16(af0, Qf[0], zf, 0, 0, 0);
            St[mi] = __builtin_amdgcn_mfma_f32_16x16x32_bf16(af1, Qf[1], s, 0, 0, 0);
        }

        // P = exp(S - 8); pack key-contiguous per query row into wave-private LDS
        #pragma unroll
        for (int mi = 0; mi < 4; mi++) {
            const f32x4 s = St[mi];
            const float p0 = __expf(s[0] - 8.f);
            const float p1 = __expf(s[1] - 8.f);
            const float p2 = __expf(s[2] - 8.f);
            const float p3 = __expf(s[3] - 8.f);
            lsum += (p0 + p1) + (p2 + p3);
            uint2 d;
            d.x = (unsigned int)f2bf(p0) | ((unsigned int)f2bf(p1) << 16);
            d.y = (unsigned int)f2bf(p2) | ((unsigned int)f2bf(p3) << 16);
            *(uint2*)&Pw[w][l15 * 72 + 16 * mi + 4 * quad] = d;
        }

        short8 Pf[2];
        #pragma unroll
        for (int ks = 0; ks < 2; ks++)
            Pf[ks] = *(const short8*)&Pw[w][l15 * 72 + 32 * ks + 8 * quad];

        // PV: V fragments straight from global (Vt rows are key-contiguous)
        #pragma unroll
        for (int ci = 0; ci < 4; ci++) {
            const short8 vf0 = *(const short8*)&Vl[(size_t)ci * 16 * 4096 + t0];
            const short8 vf1 = *(const short8*)&Vl[(size_t)ci * 16 * 4096 + t0 + 32];
            O[ci] = __builtin_amdgcn_mfma_f32_16x16x32_bf16(Pf[0], vf0, O[ci], 0, 0, 0);
            O[ci] = __builtin_amdgcn_mfma_f32_16x16x32_bf16(Pf[1], vf1, O[ci], 0, 0, 0);
        }
    }

    lsum += __shfl_xor(lsum, 16, 64);
    lsum += __shfl_xor(lsum, 32, 64);
    lsum = 1.0f / lsum;

    const size_t ob = ((size_t)(bs * 16 + qfr)) * 196608;   // 256*768
    #pragma unroll
    for (int r = 0; r < 4; r++) {
        const float inv = __shfl(lsum, quad * 4 + r, 64);
        const int pos = (qtile & 3) * 64 + w * 16 + 4 * quad + r;
        #pragma unroll
        for (int ci = 0; ci < 4; ci++) {
            const int chan = (16 * ci + l15) * 12 + head;
            OspT[ob + (size_t)pos * 768 + chan] = f2bf(O[ci][r] * inv);
        }
    }
}

// ---------------------------------------------------------------------------
// Kernel 5: projection GEMM (MFMA bf16), wide tile, + residual mix epilogue.
// ---------------------------------------------------------------------------
__global__ __launch_bounds__(256, 2) void proj_mfma_kernel(
    const unsigned short* __restrict__ Wpb,   // [768][768] bf16, scale folded
    const unsigned short* __restrict__ OspT,  // [32][256][768] bf16
    const float* __restrict__ X,
    float* __restrict__ Out)
{
    const int my = blockIdx.x;
    const int b  = blockIdx.y;
    const int m0 = my * 64;

    const int tid = threadIdx.x;
    const int w = tid >> 6, lane = tid & 63;
    const int l15 = lane & 15, quad = lane >> 4;

    __shared__ unsigned short As[64 * 72];
    __shared__ unsigned short Bs[256 * 72];

    const unsigned short* Ag = Wpb + (size_t)m0 * 768;
    const unsigned short* Bg = OspT + (size_t)b * 256 * 768;

    f32x4 acc[4][4];
    #pragma unroll
    for (int mi = 0; mi < 4; mi++)
        #pragma unroll
        for (int ni = 0; ni < 4; ni++)
            acc[mi][ni] = (f32x4){0.f, 0.f, 0.f, 0.f};

    const int arow = tid >> 2, acol = (tid & 3) * 16;
    const int brow = tid >> 3, bcol = (tid & 7) * 8;

    for (int k0 = 0; k0 < 768; k0 += 64) {
        const short8 av0 = *(const short8*)&Ag[(size_t)arow * 768 + k0 + acol];
        const short8 av1 = *(const short8*)&Ag[(size_t)arow * 768 + k0 + acol + 8];
        short8 bv[8];
        #pragma unroll
        for (int p = 0; p < 8; p++)
            bv[p] = *(const short8*)&Bg[(size_t)(32 * p + brow) * 768 + k0 + bcol];
        __syncthreads();
        *(short8*)&As[arow * 72 + acol] = av0;
        *(short8*)&As[arow * 72 + acol + 8] = av1;
        #pragma unroll
        for (int p = 0; p < 8; p++)
            *(short8*)&Bs[(32 * p + brow) * 72 + bcol] = bv[p];
        __syncthreads();

        short8 af[4][2], bfr[4][2];
        #pragma unroll
        for (int mi = 0; mi < 4; mi++)
            #pragma unroll
            for (int kk = 0; kk < 2; kk++)
                af[mi][kk] = *(const short8*)&As[(16 * mi + l15) * 72 + 32 * kk + 8 * quad];
        #pragma unroll
        for (int ni = 0; ni < 4; ni++)
            #pragma unroll
            for (int kk = 0; kk < 2; kk++)
                bfr[ni][kk] = *(const short8*)&Bs[(64 * w + 16 * ni + l15) * 72 + 32 * kk + 8 * quad];
        #pragma unroll
        for (int kk = 0; kk < 2; kk++)
            #pragma unroll
            for (int mi = 0; mi < 4; mi++)
                #pragma unroll
                for (int ni = 0; ni < 4; ni++)
                    acc[mi][ni] = __builtin_amdgcn_mfma_f32_16x16x32_bf16(af[mi][kk], bfr[ni][kk], acc[mi][ni], 0, 0, 0);
    }

    const float kMix = 1.3130643285972254f; // 1/sqrt(0.58)
    #pragma unroll
    for (int mi = 0; mi < 4; mi++)
        #pragma unroll
        for (int r = 0; r < 4; r++) {
            const int m = m0 + 16 * mi + 4 * quad + r;
            const size_t rowb = (size_t)b * 196608 + (size_t)m * 256;
            #pragma unroll
            for (int ni = 0; ni < 4; ni++) {
                const int n = 64 * w + 16 * ni + l15;
                Out[rowb + n] = (0.7f * X[rowb + n] + 0.3f * acc[mi][ni][r]) * kMix;
            }
        }
}

// ---------------------------------------------------------------------------
extern "C" void kernel_launch(void* const* d_in, const int* in_sizes, int n_in,
                              void* d_out, int out_size, void* d_ws, size_t ws_size,
                              hipStream_t stream) {
    const float* x     = (const float*)d_in[0];
    const float* wqkv  = (const float*)d_in[1];
    const float* wproj = (const float*)d_in[2];
    float* out = (float*)d_out;

    // workspace layout (~55 MB). OspT aliases XbT (dead after qkv_mfma).
    char* ws = (char*)d_ws;
    unsigned short* Wqb  = (unsigned short*)(ws + 0);          //  3,538,944 B
    unsigned short* Wpb  = (unsigned short*)(ws + 3538944);    //  1,179,648 B
    unsigned short* XbT  = (unsigned short*)(ws + 4718592);    // 12,582,912 B
    unsigned short* OspT = XbT;                                // alias
    bf16*  Q   = (bf16*)(ws + 17301504);                       // 12,582,912 B
    bf16*  K   = (bf16*)(ws + 29884416);                       // 12,582,912 B
    bf16*  Vt  = (bf16*)(ws + 42467328);                       // 12,582,912 B -> 55,050,240

    rownorm_cast_kernel<<<3072, 256, 0, stream>>>(wqkv, wproj, Wqb, Wpb);
    cast_x_kernel<<<dim3(12, 32), 256, 0, stream>>>(x, XbT);
    qkv_mfma_kernel<<<dim3(36, 32), 256, 0, stream>>>(Wqb, XbT, Q, K, Vt);
    attn_mfma_kernel<<<dim3(64, 12, 2), 256, 0, stream>>>(Q, K, Vt, OspT);
    proj_mfma_kernel<<<dim3(12, 32), 256, 0, stream>>>(Wpb, OspT, x, out);
}

// Round 9
// 307.686 us; speedup vs baseline: 2.3483x; 2.3483x over previous
//
#include <hip/hip_runtime.h>
#include <hip/hip_bf16.h>
#include <math.h>

typedef __hip_bfloat16 bf16;
typedef __attribute__((ext_vector_type(8))) short short8;
typedef __attribute__((ext_vector_type(4))) float f32x4;

#define EPSV 0.0001f

__device__ __forceinline__ unsigned short f2bf(float f) {  // RNE bf16 bits
    unsigned int u = __float_as_uint(f);
    u += 0x7fff + ((u >> 16) & 1);
    return (unsigned short)(u >> 16);
}

// ---------------------------------------------------------------------------
// Kernel 1: weight row-norm + cast to bf16 with scale folded in.
// ---------------------------------------------------------------------------
__global__ __launch_bounds__(256) void rownorm_cast_kernel(
    const float* __restrict__ w_qkv, const float* __restrict__ w_proj,
    unsigned short* __restrict__ Wqb, unsigned short* __restrict__ Wpb)
{
    const int row = blockIdx.x;
    const float* src;
    unsigned short* dst;
    if (row < 2304) { src = w_qkv + (size_t)row * 768;           dst = Wqb + (size_t)row * 768; }
    else            { src = w_proj + (size_t)(row - 2304) * 768; dst = Wpb + (size_t)(row - 2304) * 768; }

    const int tid = threadIdx.x;
    float v[3];
    float ss = 0.f;
    #pragma unroll
    for (int j = 0; j < 3; j++) {
        v[j] = src[tid + j * 256];
        ss += v[j] * v[j];
    }
    #pragma unroll
    for (int off = 32; off > 0; off >>= 1) ss += __shfl_down(ss, off, 64);
    __shared__ float wsum[4];
    if ((tid & 63) == 0) wsum[tid >> 6] = ss;
    __syncthreads();
    const float total = wsum[0] + wsum[1] + wsum[2] + wsum[3];
    const float scale = 1.0f / (EPSV * 27.712812921102035f + sqrtf(total)); // sqrt(768)
    #pragma unroll
    for (int j = 0; j < 3; j++) dst[tid + j * 256] = f2bf(v[j] * scale);
}

// ---------------------------------------------------------------------------
// Kernel 2: X [32][768][256] fp32 -> XbT [32][256][768] bf16 (transposed).
// ---------------------------------------------------------------------------
__global__ __launch_bounds__(256) void cast_x_kernel(
    const float* __restrict__ X, unsigned short* __restrict__ XbT)
{
    const int c0 = blockIdx.x * 64;
    const int b  = blockIdx.y;
    const int pos = threadIdx.x;
    const float* src = X + ((size_t)b * 768 + c0) * 256 + pos;
    unsigned short* dst = XbT + ((size_t)b * 256 + pos) * 768 + c0;
    #pragma unroll
    for (int cc = 0; cc < 8; cc++) {
        short8 t;
        #pragma unroll
        for (int j = 0; j < 8; j++)
            t[j] = (short)f2bf(src[(size_t)(cc * 8 + j) * 256]);
        *(short8*)&dst[cc * 8] = t;
    }
}

// ---------------------------------------------------------------------------
// Kernel 3: QKV GEMM (MFMA bf16), wide tile (round-6 structure).
// ---------------------------------------------------------------------------
__global__ __launch_bounds__(256, 2) void qkv_mfma_kernel(
    const unsigned short* __restrict__ Wqb,  // [2304][768] bf16, scale folded
    const unsigned short* __restrict__ XbT,  // [32][256][768] bf16
    bf16* __restrict__ Q, bf16* __restrict__ K, bf16* __restrict__ Vt)
{
    const int g = blockIdx.x;            // 0..35 (= qkv*12 + head)
    const int b = blockIdx.y;            // 0..31 (= bs*16 + fr)
    const int bs = b >> 4, fr = b & 15;
    const int qkv = g / 12, head = g % 12;
    const int m0 = g * 64;

    const int tid = threadIdx.x;
    const int w = tid >> 6, lane = tid & 63;
    const int l15 = lane & 15, quad = lane >> 4;

    __shared__ unsigned short As[64 * 72];
    __shared__ unsigned short Bs[256 * 72];

    const unsigned short* Ag = Wqb + (size_t)m0 * 768;
    const unsigned short* Bg = XbT + (size_t)b * 256 * 768;

    f32x4 acc[4][4];   // [mi][ni]
    #pragma unroll
    for (int mi = 0; mi < 4; mi++)
        #pragma unroll
        for (int ni = 0; ni < 4; ni++)
            acc[mi][ni] = (f32x4){0.f, 0.f, 0.f, 0.f};

    const int arow = tid >> 2, acol = (tid & 3) * 16;
    const int brow = tid >> 3, bcol = (tid & 7) * 8;

    for (int k0 = 0; k0 < 768; k0 += 64) {
        const short8 av0 = *(const short8*)&Ag[(size_t)arow * 768 + k0 + acol];
        const short8 av1 = *(const short8*)&Ag[(size_t)arow * 768 + k0 + acol + 8];
        short8 bv[8];
        #pragma unroll
        for (int p = 0; p < 8; p++)
            bv[p] = *(const short8*)&Bg[(size_t)(32 * p + brow) * 768 + k0 + bcol];
        __syncthreads();
        *(short8*)&As[arow * 72 + acol] = av0;
        *(short8*)&As[arow * 72 + acol + 8] = av1;
        #pragma unroll
        for (int p = 0; p < 8; p++)
            *(short8*)&Bs[(32 * p + brow) * 72 + bcol] = bv[p];
        __syncthreads();

        short8 af[4][2], bfr[4][2];
        #pragma unroll
        for (int mi = 0; mi < 4; mi++)
            #pragma unroll
            for (int kk = 0; kk < 2; kk++)
                af[mi][kk] = *(const short8*)&As[(16 * mi + l15) * 72 + 32 * kk + 8 * quad];
        #pragma unroll
        for (int ni = 0; ni < 4; ni++)
            #pragma unroll
            for (int kk = 0; kk < 2; kk++)
                bfr[ni][kk] = *(const short8*)&Bs[(64 * w + 16 * ni + l15) * 72 + 32 * kk + 8 * quad];
        #pragma unroll
        for (int kk = 0; kk < 2; kk++)
            #pragma unroll
            for (int mi = 0; mi < 4; mi++)
                #pragma unroll
                for (int ni = 0; ni < 4; ni++)
                    acc[mi][ni] = __builtin_amdgcn_mfma_f32_16x16x32_bf16(af[mi][kk], bfr[ni][kk], acc[mi][ni], 0, 0, 0);
    }

    float inv[4];
    #pragma unroll
    for (int ni = 0; ni < 4; ni++) {
        float ssq = 0.f;
        #pragma unroll
        for (int mi = 0; mi < 4; mi++)
            #pragma unroll
            for (int r = 0; r < 4; r++)
                ssq = fmaf(acc[mi][ni][r], acc[mi][ni][r], ssq);
        ssq += __shfl_xor(ssq, 16, 64);
        ssq += __shfl_xor(ssq, 32, 64);
        inv[ni] = 1.0f / (EPSV + sqrtf(ssq) * 0.125f);
    }

    if (qkv == 2) {
        unsigned short* Vb = &Bs[w * 64 * 72];
        #pragma unroll
        for (int ni = 0; ni < 4; ni++)
            #pragma unroll
            for (int mi = 0; mi < 4; mi++) {
                uint2 d;
                d.x = (unsigned int)f2bf(acc[mi][ni][0] * inv[ni]) |
                      ((unsigned int)f2bf(acc[mi][ni][1] * inv[ni]) << 16);
                d.y = (unsigned int)f2bf(acc[mi][ni][2] * inv[ni]) |
                      ((unsigned int)f2bf(acc[mi][ni][3] * inv[ni]) << 16);
                *(uint2*)&Vb[(16 * ni + l15) * 72 + 16 * mi + 4 * quad] = d;
            }
        unsigned short* Vtu = (unsigned short*)Vt;
        const size_t cb = ((size_t)(bs * 12 + head) * 64);
        const int tok = fr * 256 + 64 * w + lane;
        #pragma unroll 8
        for (int ch = 0; ch < 64; ch++)
            Vtu[(cb + ch) * 4096 + tok] = Vb[lane * 72 + ch];
    } else {
        unsigned short* dst = (unsigned short*)((qkv == 0) ? Q : K);
        const float post = (qkv == 0) ? 0.125f : 1.0f;   // fold 1/sqrt(c) into Q
        #pragma unroll
        for (int ni = 0; ni < 4; ni++) {
            const int token = fr * 256 + 64 * w + 16 * ni + l15;
            const size_t base = (((size_t)(bs * 12 + head)) * 4096 + token) * 64;
            #pragma unroll
            for (int mi = 0; mi < 2; mi++) {
                unsigned int lo[2], hi[2];
                #pragma unroll
                for (int r = 0; r < 4; r++) {
                    const int j = 16 * mi + 4 * quad + r;
                    const float n1 = acc[mi][ni][r] * inv[ni];
                    const float n2 = acc[mi + 2][ni][r] * inv[ni];
                    const float ang = (float)fr * exp2f(-(float)j * 0.41524101186092029f);
                    float sn, cs;
                    __sincosf(ang, &sn, &cs);
                    const unsigned short o1 = f2bf((n1 * cs - n2 * sn) * post);
                    const unsigned short o2 = f2bf((n2 * cs + n1 * sn) * post);
                    if (r < 2) { if (r == 0) { lo[0] = o1; hi[0] = o2; } else { lo[0] |= (unsigned int)o1 << 16; hi[0] |= (unsigned int)o2 << 16; } }
                    else       { if (r == 2) { lo[1] = o1; hi[1] = o2; } else { lo[1] |= (unsigned int)o1 << 16; hi[1] |= (unsigned int)o2 << 16; } }
                }
                *(uint2*)&dst[base + 16 * mi + 4 * quad]      = make_uint2(lo[0], lo[1]);
                *(uint2*)&dst[base + 32 + 16 * mi + 4 * quad] = make_uint2(hi[0], hi[1]);
            }
        }
    }
}

// ---------------------------------------------------------------------------
// Kernel 4: MFMA flash attention, frame-causal. LDS-staged K/V (round-7
// structure) + REGISTER DOUBLE-BUFFER: next chunk's global loads issue
// during current chunk's compute, so the reg->LDS write after the barrier
// doesn't wait on memory. LDS 23.0 KB -> 6 blocks/CU.
// ---------------------------------------------------------------------------
__global__ __launch_bounds__(256, 4) void attn_mfma_kernel(
    const bf16* __restrict__ Qg, const bf16* __restrict__ Kg,
    const bf16* __restrict__ Vtg, unsigned short* __restrict__ OspT)
{
    const int qtile = 63 - blockIdx.x;           // heavy first
    const int qfr = qtile >> 2;
    const int head = blockIdx.y, bs = blockIdx.z;
    const int tid = threadIdx.x;
    const int w = tid >> 6, lane = tid & 63;
    const int l15 = lane & 15, quad = lane >> 4;
    const size_t hb = ((size_t)(bs * 12 + head)) * 4096 * 64;

    __shared__ unsigned short Ks[64 * 72];       //  9.2 KB
    __shared__ unsigned short Vs[64 * 72];       //  9.2 KB
    __shared__ unsigned short Pw[4][16 * 40];    //  5.1 KB (stride 40: 80 B, 16B-aligned rows)

    const unsigned short* Qu = (const unsigned short*)Qg;
    const unsigned short* Ku = (const unsigned short*)Kg;
    const unsigned short* Vu = (const unsigned short*)Vtg;

    short8 Qf[2];
    {
        const int qrow = qfr * 256 + (qtile & 3) * 64 + w * 16 + l15;
        #pragma unroll
        for (int kk = 0; kk < 2; kk++)
            Qf[kk] = *(const short8*)&Qu[hb + (size_t)qrow * 64 + 32 * kk + 8 * quad];
    }

    f32x4 O[4];
    #pragma unroll
    for (int c = 0; c < 4; c++) O[c] = (f32x4){0.f, 0.f, 0.f, 0.f};
    float lsum = 0.f;
    const f32x4 zf = (f32x4){0.f, 0.f, 0.f, 0.f};

    const int stage_row = tid >> 2;
    const int stage_off = (tid & 3) * 16;
    const unsigned short* Kst = Ku + hb + stage_off;                          // + (t0+stage_row)*64
    const unsigned short* Vst = Vu + hb + (size_t)stage_row * 4096 + stage_off; // + t0

    // prefetch chunk 0
    short8 ka = *(const short8*)&Kst[(size_t)stage_row * 64];
    short8 kb = *(const short8*)&Kst[(size_t)stage_row * 64 + 8];
    short8 va = *(const short8*)&Vst[0];
    short8 vb = *(const short8*)&Vst[8];

    const int nk = (qfr + 1) * 256;
    for (int t0 = 0; t0 < nk; t0 += 64) {
        __syncthreads();                         // prior chunk's LDS reads done
        *(short8*)&Ks[stage_row * 72 + stage_off] = ka;
        *(short8*)&Ks[stage_row * 72 + stage_off + 8] = kb;
        *(short8*)&Vs[stage_row * 72 + stage_off] = va;
        *(short8*)&Vs[stage_row * 72 + stage_off + 8] = vb;
        __syncthreads();

        // issue next chunk's loads now; latency hides under the MFMAs below
        const int tn = (t0 + 64 < nk) ? t0 + 64 : t0;
        ka = *(const short8*)&Kst[(size_t)(tn + stage_row) * 64];
        kb = *(const short8*)&Kst[(size_t)(tn + stage_row) * 64 + 8];
        va = *(const short8*)&Vst[tn];
        vb = *(const short8*)&Vst[tn + 8];

        // S^T = K · Q^T : lane holds query l15, keys 16mi+4quad+r
        f32x4 St[4];
        #pragma unroll
        for (int mi = 0; mi < 4; mi++) {
            const short8 kf0 = *(const short8*)&Ks[(16 * mi + l15) * 72 + 8 * quad];
            const short8 kf1 = *(const short8*)&Ks[(16 * mi + l15) * 72 + 32 + 8 * quad];
            f32x4 s = __builtin_amdgcn_mfma_f32_16x16x32_bf16(kf0, Qf[0], zf, 0, 0, 0);
            St[mi] = __builtin_amdgcn_mfma_f32_16x16x32_bf16(kf1, Qf[1], s, 0, 0, 0);
        }

        // P = exp(S - 8), packed key-contiguous per query row (wave-private)
        #pragma unroll
        for (int mi = 0; mi < 4; mi++) {
            const f32x4 s = St[mi];
            const float p0 = __expf(s[0] - 8.f);
            const float p1 = __expf(s[1] - 8.f);
            const float p2 = __expf(s[2] - 8.f);
            const float p3 = __expf(s[3] - 8.f);
            lsum += (p0 + p1) + (p2 + p3);
            uint2 d;
            d.x = (unsigned int)f2bf(p0) | ((unsigned int)f2bf(p1) << 16);
            d.y = (unsigned int)f2bf(p2) | ((unsigned int)f2bf(p3) << 16);
            *(uint2*)&Pw[w][l15 * 40 + 16 * mi + 4 * quad] = d;
        }

        short8 Pf[2];
        #pragma unroll
        for (int ks = 0; ks < 2; ks++)
            Pf[ks] = *(const short8*)&Pw[w][l15 * 40 + 32 * ks + 8 * quad];

        #pragma unroll
        for (int ci = 0; ci < 4; ci++) {
            const short8 vf0 = *(const short8*)&Vs[(16 * ci + l15) * 72 + 8 * quad];
            const short8 vf1 = *(const short8*)&Vs[(16 * ci + l15) * 72 + 32 + 8 * quad];
            O[ci] = __builtin_amdgcn_mfma_f32_16x16x32_bf16(Pf[0], vf0, O[ci], 0, 0, 0);
            O[ci] = __builtin_amdgcn_mfma_f32_16x16x32_bf16(Pf[1], vf1, O[ci], 0, 0, 0);
        }
    }

    lsum += __shfl_xor(lsum, 16, 64);
    lsum += __shfl_xor(lsum, 32, 64);
    lsum = 1.0f / lsum;

    const size_t ob = ((size_t)(bs * 16 + qfr)) * 196608;   // 256*768
    #pragma unroll
    for (int r = 0; r < 4; r++) {
        const float inv = __shfl(lsum, quad * 4 + r, 64);
        const int pos = (qtile & 3) * 64 + w * 16 + 4 * quad + r;
        #pragma unroll
        for (int ci = 0; ci < 4; ci++) {
            const int chan = (16 * ci + l15) * 12 + head;
            OspT[ob + (size_t)pos * 768 + chan] = f2bf(O[ci][r] * inv);
        }
    }
}

// ---------------------------------------------------------------------------
// Kernel 5: projection GEMM (MFMA bf16), wide tile, + residual mix epilogue.
// ---------------------------------------------------------------------------
__global__ __launch_bounds__(256, 2) void proj_mfma_kernel(
    const unsigned short* __restrict__ Wpb,   // [768][768] bf16, scale folded
    const unsigned short* __restrict__ OspT,  // [32][256][768] bf16
    const float* __restrict__ X,
    float* __restrict__ Out)
{
    const int my = blockIdx.x;
    const int b  = blockIdx.y;
    const int m0 = my * 64;

    const int tid = threadIdx.x;
    const int w = tid >> 6, lane = tid & 63;
    const int l15 = lane & 15, quad = lane >> 4;

    __shared__ unsigned short As[64 * 72];
    __shared__ unsigned short Bs[256 * 72];

    const unsigned short* Ag = Wpb + (size_t)m0 * 768;
    const unsigned short* Bg = OspT + (size_t)b * 256 * 768;

    f32x4 acc[4][4];
    #pragma unroll
    for (int mi = 0; mi < 4; mi++)
        #pragma unroll
        for (int ni = 0; ni < 4; ni++)
            acc[mi][ni] = (f32x4){0.f, 0.f, 0.f, 0.f};

    const int arow = tid >> 2, acol = (tid & 3) * 16;
    const int brow = tid >> 3, bcol = (tid & 7) * 8;

    for (int k0 = 0; k0 < 768; k0 += 64) {
        const short8 av0 = *(const short8*)&Ag[(size_t)arow * 768 + k0 + acol];
        const short8 av1 = *(const short8*)&Ag[(size_t)arow * 768 + k0 + acol + 8];
        short8 bv[8];
        #pragma unroll
        for (int p = 0; p < 8; p++)
            bv[p] = *(const short8*)&Bg[(size_t)(32 * p + brow) * 768 + k0 + bcol];
        __syncthreads();
        *(short8*)&As[arow * 72 + acol] = av0;
        *(short8*)&As[arow * 72 + acol + 8] = av1;
        #pragma unroll
        for (int p = 0; p < 8; p++)
            *(short8*)&Bs[(32 * p + brow) * 72 + bcol] = bv[p];
        __syncthreads();

        short8 af[4][2], bfr[4][2];
        #pragma unroll
        for (int mi = 0; mi < 4; mi++)
            #pragma unroll
            for (int kk = 0; kk < 2; kk++)
                af[mi][kk] = *(const short8*)&As[(16 * mi + l15) * 72 + 32 * kk + 8 * quad];
        #pragma unroll
        for (int ni = 0; ni < 4; ni++)
            #pragma unroll
            for (int kk = 0; kk < 2; kk++)
                bfr[ni][kk] = *(const short8*)&Bs[(64 * w + 16 * ni + l15) * 72 + 32 * kk + 8 * quad];
        #pragma unroll
        for (int kk = 0; kk < 2; kk++)
            #pragma unroll
            for (int mi = 0; mi < 4; mi++)
                #pragma unroll
                for (int ni = 0; ni < 4; ni++)
                    acc[mi][ni] = __builtin_amdgcn_mfma_f32_16x16x32_bf16(af[mi][kk], bfr[ni][kk], acc[mi][ni], 0, 0, 0);
    }

    const float kMix = 1.3130643285972254f; // 1/sqrt(0.58)
    #pragma unroll
    for (int mi = 0; mi < 4; mi++)
        #pragma unroll
        for (int r = 0; r < 4; r++) {
            const int m = m0 + 16 * mi + 4 * quad + r;
            const size_t rowb = (size_t)b * 196608 + (size_t)m * 256;
            #pragma unroll
            for (int ni = 0; ni < 4; ni++) {
                const int n = 64 * w + 16 * ni + l15;
                Out[rowb + n] = (0.7f * X[rowb + n] + 0.3f * acc[mi][ni][r]) * kMix;
            }
        }
}

// ---------------------------------------------------------------------------
extern "C" void kernel_launch(void* const* d_in, const int* in_sizes, int n_in,
                              void* d_out, int out_size, void* d_ws, size_t ws_size,
                              hipStream_t stream) {
    const float* x     = (const float*)d_in[0];
    const float* wqkv  = (const float*)d_in[1];
    const float* wproj = (const float*)d_in[2];
    float* out = (float*)d_out;

    // workspace layout (~55 MB). OspT aliases XbT (dead after qkv_mfma).
    char* ws = (char*)d_ws;
    unsigned short* Wqb  = (unsigned short*)(ws + 0);          //  3,538,944 B
    unsigned short* Wpb  = (unsigned short*)(ws + 3538944);    //  1,179,648 B
    unsigned short* XbT  = (unsigned short*)(ws + 4718592);    // 12,582,912 B
    unsigned short* OspT = XbT;                                // alias
    bf16*  Q   = (bf16*)(ws + 17301504);                       // 12,582,912 B
    bf16*  K   = (bf16*)(ws + 29884416);                       // 12,582,912 B
    bf16*  Vt  = (bf16*)(ws + 42467328);                       // 12,582,912 B -> 55,050,240

    rownorm_cast_kernel<<<3072, 256, 0, stream>>>(wqkv, wproj, Wqb, Wpb);
    cast_x_kernel<<<dim3(12, 32), 256, 0, stream>>>(x, XbT);
    qkv_mfma_kernel<<<dim3(36, 32), 256, 0, stream>>>(Wqb, XbT, Q, K, Vt);
    attn_mfma_kernel<<<dim3(64, 12, 2), 256, 0, stream>>>(Q, K, Vt, OspT);
    proj_mfma_kernel<<<dim3(12, 32), 256, 0, stream>>>(Wpb, OspT, x, out);
}

// Round 13
// 261.346 us; speedup vs baseline: 2.7646x; 1.1773x over previous
//
#include <hip/hip_runtime.h>
#include <hip/hip_bf16.h>
#include <math.h>

typedef __hip_bfloat16 bf16;
typedef __attribute__((ext_vector_type(8))) short short8;
typedef __attribute__((ext_vector_type(4))) float f32x4;

#define EPSV 0.0001f

__device__ __forceinline__ unsigned short f2bf(float f) {  // RNE bf16 bits
    unsigned int u = __float_as_uint(f);
    u += 0x7fff + ((u >> 16) & 1);
    return (unsigned short)(u >> 16);
}
__device__ __forceinline__ unsigned int pkbf(float a, float b) {  // v_cvt_pk_bf16_f32
    __hip_bfloat162 h = __float22bfloat162_rn(make_float2(a, b));
    return *(unsigned int*)&h;
}
__device__ __forceinline__ float fast_exp2(float x) {      // v_exp_f32
    return __builtin_amdgcn_exp2f(x);
}

// ---------------------------------------------------------------------------
// Kernel 1: weight row-norm + cast to bf16 with scale folded in.
// ---------------------------------------------------------------------------
__global__ __launch_bounds__(256) void rownorm_cast_kernel(
    const float* __restrict__ w_qkv, const float* __restrict__ w_proj,
    unsigned short* __restrict__ Wqb, unsigned short* __restrict__ Wpb)
{
    const int row = blockIdx.x;
    const float* src;
    unsigned short* dst;
    if (row < 2304) { src = w_qkv + (size_t)row * 768;           dst = Wqb + (size_t)row * 768; }
    else            { src = w_proj + (size_t)(row - 2304) * 768; dst = Wpb + (size_t)(row - 2304) * 768; }

    const int tid = threadIdx.x;
    float v[3];
    float ss = 0.f;
    #pragma unroll
    for (int j = 0; j < 3; j++) {
        v[j] = src[tid + j * 256];
        ss += v[j] * v[j];
    }
    #pragma unroll
    for (int off = 32; off > 0; off >>= 1) ss += __shfl_down(ss, off, 64);
    __shared__ float wsum[4];
    if ((tid & 63) == 0) wsum[tid >> 6] = ss;
    __syncthreads();
    const float total = wsum[0] + wsum[1] + wsum[2] + wsum[3];
    const float scale = 1.0f / (EPSV * 27.712812921102035f + sqrtf(total)); // sqrt(768)
    #pragma unroll
    for (int j = 0; j < 3; j++) dst[tid + j * 256] = f2bf(v[j] * scale);
}

// ---------------------------------------------------------------------------
// Kernel 2: X [32][768][256] fp32 -> XbT [32][256][768] bf16 (transposed).
// ---------------------------------------------------------------------------
__global__ __launch_bounds__(256) void cast_x_kernel(
    const float* __restrict__ X, unsigned short* __restrict__ XbT)
{
    const int c0 = blockIdx.x * 64;
    const int b  = blockIdx.y;
    const int pos = threadIdx.x;
    const float* src = X + ((size_t)b * 768 + c0) * 256 + pos;
    unsigned short* dst = XbT + ((size_t)b * 256 + pos) * 768 + c0;
    #pragma unroll
    for (int cc = 0; cc < 8; cc++) {
        short8 t;
        #pragma unroll
        for (int j = 0; j < 8; j++)
            t[j] = (short)f2bf(src[(size_t)(cc * 8 + j) * 256]);
        *(short8*)&dst[cc * 8] = t;
    }
}

// ---------------------------------------------------------------------------
// Kernel 3: QKV GEMM (MFMA bf16), wide tile. Q pre-scaled by 0.125 (EXACT
// power-of-two — folding non-pow2 constants into bf16 Q costs accuracy).
// ---------------------------------------------------------------------------
__global__ __launch_bounds__(256, 2) void qkv_mfma_kernel(
    const unsigned short* __restrict__ Wqb,  // [2304][768] bf16, scale folded
    const unsigned short* __restrict__ XbT,  // [32][256][768] bf16
    bf16* __restrict__ Q, bf16* __restrict__ K, bf16* __restrict__ Vt)
{
    const int g = blockIdx.x;            // 0..35 (= qkv*12 + head)
    const int b = blockIdx.y;            // 0..31 (= bs*16 + fr)
    const int bs = b >> 4, fr = b & 15;
    const int qkv = g / 12, head = g % 12;
    const int m0 = g * 64;

    const int tid = threadIdx.x;
    const int w = tid >> 6, lane = tid & 63;
    const int l15 = lane & 15, quad = lane >> 4;

    __shared__ unsigned short As[64 * 72];
    __shared__ unsigned short Bs[256 * 72];

    const unsigned short* Ag = Wqb + (size_t)m0 * 768;
    const unsigned short* Bg = XbT + (size_t)b * 256 * 768;

    f32x4 acc[4][4];   // [mi][ni]
    #pragma unroll
    for (int mi = 0; mi < 4; mi++)
        #pragma unroll
        for (int ni = 0; ni < 4; ni++)
            acc[mi][ni] = (f32x4){0.f, 0.f, 0.f, 0.f};

    const int arow = tid >> 2, acol = (tid & 3) * 16;
    const int brow = tid >> 3, bcol = (tid & 7) * 8;

    for (int k0 = 0; k0 < 768; k0 += 64) {
        const short8 av0 = *(const short8*)&Ag[(size_t)arow * 768 + k0 + acol];
        const short8 av1 = *(const short8*)&Ag[(size_t)arow * 768 + k0 + acol + 8];
        short8 bv[8];
        #pragma unroll
        for (int p = 0; p < 8; p++)
            bv[p] = *(const short8*)&Bg[(size_t)(32 * p + brow) * 768 + k0 + bcol];
        __syncthreads();
        *(short8*)&As[arow * 72 + acol] = av0;
        *(short8*)&As[arow * 72 + acol + 8] = av1;
        #pragma unroll
        for (int p = 0; p < 8; p++)
            *(short8*)&Bs[(32 * p + brow) * 72 + bcol] = bv[p];
        __syncthreads();

        short8 af[4][2], bfr[4][2];
        #pragma unroll
        for (int mi = 0; mi < 4; mi++)
            #pragma unroll
            for (int kk = 0; kk < 2; kk++)
                af[mi][kk] = *(const short8*)&As[(16 * mi + l15) * 72 + 32 * kk + 8 * quad];
        #pragma unroll
        for (int ni = 0; ni < 4; ni++)
            #pragma unroll
            for (int kk = 0; kk < 2; kk++)
                bfr[ni][kk] = *(const short8*)&Bs[(64 * w + 16 * ni + l15) * 72 + 32 * kk + 8 * quad];
        #pragma unroll
        for (int kk = 0; kk < 2; kk++)
            #pragma unroll
            for (int mi = 0; mi < 4; mi++)
                #pragma unroll
                for (int ni = 0; ni < 4; ni++)
                    acc[mi][ni] = __builtin_amdgcn_mfma_f32_16x16x32_bf16(af[mi][kk], bfr[ni][kk], acc[mi][ni], 0, 0, 0);
    }

    float inv[4];
    #pragma unroll
    for (int ni = 0; ni < 4; ni++) {
        float ssq = 0.f;
        #pragma unroll
        for (int mi = 0; mi < 4; mi++)
            #pragma unroll
            for (int r = 0; r < 4; r++)
                ssq = fmaf(acc[mi][ni][r], acc[mi][ni][r], ssq);
        ssq += __shfl_xor(ssq, 16, 64);
        ssq += __shfl_xor(ssq, 32, 64);
        inv[ni] = 1.0f / (EPSV + sqrtf(ssq) * 0.125f);
    }

    if (qkv == 2) {
        unsigned short* Vb = &Bs[w * 64 * 72];
        #pragma unroll
        for (int ni = 0; ni < 4; ni++)
            #pragma unroll
            for (int mi = 0; mi < 4; mi++) {
                uint2 d;
                d.x = pkbf(acc[mi][ni][0] * inv[ni], acc[mi][ni][1] * inv[ni]);
                d.y = pkbf(acc[mi][ni][2] * inv[ni], acc[mi][ni][3] * inv[ni]);
                *(uint2*)&Vb[(16 * ni + l15) * 72 + 16 * mi + 4 * quad] = d;
            }
        unsigned short* Vtu = (unsigned short*)Vt;
        const size_t cb = ((size_t)(bs * 12 + head) * 64);
        const int tok = fr * 256 + 64 * w + lane;
        #pragma unroll 8
        for (int ch = 0; ch < 64; ch++)
            Vtu[(cb + ch) * 4096 + tok] = Vb[lane * 72 + ch];
    } else {
        unsigned short* dst = (unsigned short*)((qkv == 0) ? Q : K);
        const float post = (qkv == 0) ? 0.125f : 1.0f;   // exact pow2 only
        #pragma unroll
        for (int ni = 0; ni < 4; ni++) {
            const int token = fr * 256 + 64 * w + 16 * ni + l15;
            const size_t base = (((size_t)(bs * 12 + head)) * 4096 + token) * 64;
            #pragma unroll
            for (int mi = 0; mi < 2; mi++) {
                unsigned int lo[2], hi[2];
                #pragma unroll
                for (int r = 0; r < 4; r++) {
                    const int j = 16 * mi + 4 * quad + r;
                    const float n1 = acc[mi][ni][r] * inv[ni];
                    const float n2 = acc[mi + 2][ni][r] * inv[ni];
                    const float ang = (float)fr * exp2f(-(float)j * 0.41524101186092029f);
                    float sn, cs;
                    __sincosf(ang, &sn, &cs);
                    const unsigned short o1 = f2bf((n1 * cs - n2 * sn) * post);
                    const unsigned short o2 = f2bf((n2 * cs + n1 * sn) * post);
                    if (r < 2) { if (r == 0) { lo[0] = o1; hi[0] = o2; } else { lo[0] |= (unsigned int)o1 << 16; hi[0] |= (unsigned int)o2 << 16; } }
                    else       { if (r == 2) { lo[1] = o1; hi[1] = o2; } else { lo[1] |= (unsigned int)o1 << 16; hi[1] |= (unsigned int)o2 << 16; } }
                }
                *(uint2*)&dst[base + 16 * mi + 4 * quad]      = make_uint2(lo[0], lo[1]);
                *(uint2*)&dst[base + 32 + 16 * mi + 4 * quad] = make_uint2(hi[0], hi[1]);
            }
        }
    }
}

// ---------------------------------------------------------------------------
// Kernel 4: MFMA flash attention, frame-causal, FRAME-PAIRED blocks.
// Pw rows are stride-72 (row span 64 <= 72): NO row overlap, NO slice
// overflow — the stride-40 layout overflowed tile-a row 15 into tile-b
// row 0 (the round-11/12 0.146 absmax bug).
// ---------------------------------------------------------------------------
__global__ __launch_bounds__(256, 3) void attn_mfma_kernel(
    const bf16* __restrict__ Qg, const bf16* __restrict__ Kg,
    const bf16* __restrict__ Vtg, unsigned short* __restrict__ OspT)
{
    const int px = blockIdx.x;                  // 0..31
    const int p = px >> 2, sub = px & 3;
    const int fa = p, fb = 15 - p;              // light / heavy frame
    const int head = blockIdx.y, bs = blockIdx.z;
    const int tid = threadIdx.x;
    const int w = tid >> 6, lane = tid & 63;
    const int l15 = lane & 15, quad = lane >> 4;
    const size_t hb = ((size_t)(bs * 12 + head)) * 4096 * 64;

    __shared__ unsigned short Ks[64 * 72];        //  9.2 KB
    __shared__ unsigned short Vs[64 * 72];        //  9.2 KB
    __shared__ unsigned short Pw[4][2][16 * 72];  // 18.4 KB (stride 72, safe)

    const unsigned short* Qu = (const unsigned short*)Qg;
    const unsigned short* Ku = (const unsigned short*)Kg;
    const unsigned short* Vu = (const unsigned short*)Vtg;

    short8 Qfa[2], Qfb[2];
    {
        const int qra = fa * 256 + sub * 64 + w * 16 + l15;
        const int qrb = fb * 256 + sub * 64 + w * 16 + l15;
        #pragma unroll
        for (int kk = 0; kk < 2; kk++) {
            Qfa[kk] = *(const short8*)&Qu[hb + (size_t)qra * 64 + 32 * kk + 8 * quad];
            Qfb[kk] = *(const short8*)&Qu[hb + (size_t)qrb * 64 + 32 * kk + 8 * quad];
        }
    }

    f32x4 Oa[4], Ob[4];
    #pragma unroll
    for (int c = 0; c < 4; c++) {
        Oa[c] = (f32x4){0.f, 0.f, 0.f, 0.f};
        Ob[c] = (f32x4){0.f, 0.f, 0.f, 0.f};
    }
    float la = 0.f, lb = 0.f;
    const f32x4 zf = (f32x4){0.f, 0.f, 0.f, 0.f};
    const float L2E = 1.4426950408889634f;
    const float C = 11.541560327111707f;          // 8 * log2(e)

    const int stage_row = tid >> 2;
    const int stage_off = (tid & 3) * 16;
    const unsigned short* Kst = Ku + hb + stage_off;
    const unsigned short* Vst = Vu + hb + (size_t)stage_row * 4096 + stage_off;

    // prefetch chunk 0
    short8 ka = *(const short8*)&Kst[(size_t)stage_row * 64];
    short8 kb = *(const short8*)&Kst[(size_t)stage_row * 64 + 8];
    short8 va = *(const short8*)&Vst[0];
    short8 vb = *(const short8*)&Vst[8];

    const int nka = (fa + 1) * 256;
    const int nkb = (fb + 1) * 256;
    for (int t0 = 0; t0 < nkb; t0 += 64) {
        __syncthreads();
        *(short8*)&Ks[stage_row * 72 + stage_off] = ka;
        *(short8*)&Ks[stage_row * 72 + stage_off + 8] = kb;
        *(short8*)&Vs[stage_row * 72 + stage_off] = va;
        *(short8*)&Vs[stage_row * 72 + stage_off + 8] = vb;
        __syncthreads();

        const int tn = (t0 + 64 < nkb) ? t0 + 64 : t0;
        ka = *(const short8*)&Kst[(size_t)(tn + stage_row) * 64];
        kb = *(const short8*)&Kst[(size_t)(tn + stage_row) * 64 + 8];
        va = *(const short8*)&Vst[tn];
        vb = *(const short8*)&Vst[tn + 8];

        const bool doA = (t0 < nka);   // block-uniform branch

        // S^T = K · Q^T — kf fragments shared between both query tiles
        f32x4 Sa[4], Sb[4];
        #pragma unroll
        for (int mi = 0; mi < 4; mi++) {
            const short8 kf0 = *(const short8*)&Ks[(16 * mi + l15) * 72 + 8 * quad];
            const short8 kf1 = *(const short8*)&Ks[(16 * mi + l15) * 72 + 32 + 8 * quad];
            f32x4 s = __builtin_amdgcn_mfma_f32_16x16x32_bf16(kf0, Qfb[0], zf, 0, 0, 0);
            Sb[mi] = __builtin_amdgcn_mfma_f32_16x16x32_bf16(kf1, Qfb[1], s, 0, 0, 0);
            if (doA) {
                f32x4 sa = __builtin_amdgcn_mfma_f32_16x16x32_bf16(kf0, Qfa[0], zf, 0, 0, 0);
                Sa[mi] = __builtin_amdgcn_mfma_f32_16x16x32_bf16(kf1, Qfa[1], sa, 0, 0, 0);
            }
        }

        // P = exp2(s*log2e - C), packed key-contiguous per query row
        #pragma unroll
        for (int mi = 0; mi < 4; mi++) {
            const f32x4 s = Sb[mi];
            const float p0 = fast_exp2(fmaf(s[0], L2E, -C));
            const float p1 = fast_exp2(fmaf(s[1], L2E, -C));
            const float p2 = fast_exp2(fmaf(s[2], L2E, -C));
            const float p3 = fast_exp2(fmaf(s[3], L2E, -C));
            lb += (p0 + p1) + (p2 + p3);
            uint2 d;
            d.x = pkbf(p0, p1);
            d.y = pkbf(p2, p3);
            *(uint2*)&Pw[w][1][l15 * 72 + 16 * mi + 4 * quad] = d;
        }
        if (doA) {
            #pragma unroll
            for (int mi = 0; mi < 4; mi++) {
                const f32x4 s = Sa[mi];
                const float p0 = fast_exp2(fmaf(s[0], L2E, -C));
                const float p1 = fast_exp2(fmaf(s[1], L2E, -C));
                const float p2 = fast_exp2(fmaf(s[2], L2E, -C));
                const float p3 = fast_exp2(fmaf(s[3], L2E, -C));
                la += (p0 + p1) + (p2 + p3);
                uint2 d;
                d.x = pkbf(p0, p1);
                d.y = pkbf(p2, p3);
                *(uint2*)&Pw[w][0][l15 * 72 + 16 * mi + 4 * quad] = d;
            }
        }

        short8 Pfb[2], Pfa[2];
        #pragma unroll
        for (int ks = 0; ks < 2; ks++)
            Pfb[ks] = *(const short8*)&Pw[w][1][l15 * 72 + 32 * ks + 8 * quad];
        if (doA) {
            #pragma unroll
            for (int ks = 0; ks < 2; ks++)
                Pfa[ks] = *(const short8*)&Pw[w][0][l15 * 72 + 32 * ks + 8 * quad];
        }

        // PV — vf fragments shared between both query tiles
        #pragma unroll
        for (int ci = 0; ci < 4; ci++) {
            const short8 vf0 = *(const short8*)&Vs[(16 * ci + l15) * 72 + 8 * quad];
            const short8 vf1 = *(const short8*)&Vs[(16 * ci + l15) * 72 + 32 + 8 * quad];
            Ob[ci] = __builtin_amdgcn_mfma_f32_16x16x32_bf16(Pfb[0], vf0, Ob[ci], 0, 0, 0);
            Ob[ci] = __builtin_amdgcn_mfma_f32_16x16x32_bf16(Pfb[1], vf1, Ob[ci], 0, 0, 0);
            if (doA) {
                Oa[ci] = __builtin_amdgcn_mfma_f32_16x16x32_bf16(Pfa[0], vf0, Oa[ci], 0, 0, 0);
                Oa[ci] = __builtin_amdgcn_mfma_f32_16x16x32_bf16(Pfa[1], vf1, Oa[ci], 0, 0, 0);
            }
        }
    }

    la += __shfl_xor(la, 16, 64);
    la += __shfl_xor(la, 32, 64);
    la = 1.0f / la;
    lb += __shfl_xor(lb, 16, 64);
    lb += __shfl_xor(lb, 32, 64);
    lb = 1.0f / lb;

    // epilogue for both query tiles
    const size_t oba = ((size_t)(bs * 16 + fa)) * 196608;
    const size_t obb = ((size_t)(bs * 16 + fb)) * 196608;
    #pragma unroll
    for (int r = 0; r < 4; r++) {
        const float ia = __shfl(la, quad * 4 + r, 64);
        const float ib = __shfl(lb, quad * 4 + r, 64);
        const int pos = sub * 64 + w * 16 + 4 * quad + r;
        #pragma unroll
        for (int ci = 0; ci < 4; ci++) {
            const int chan = (16 * ci + l15) * 12 + head;
            OspT[oba + (size_t)pos * 768 + chan] = f2bf(Oa[ci][r] * ia);
            OspT[obb + (size_t)pos * 768 + chan] = f2bf(Ob[ci][r] * ib);
        }
    }
}

// ---------------------------------------------------------------------------
// Kernel 5: projection GEMM (MFMA bf16), wide tile, + residual mix epilogue.
// ---------------------------------------------------------------------------
__global__ __launch_bounds__(256, 2) void proj_mfma_kernel(
    const unsigned short* __restrict__ Wpb,   // [768][768] bf16, scale folded
    const unsigned short* __restrict__ OspT,  // [32][256][768] bf16
    const float* __restrict__ X,
    float* __restrict__ Out)
{
    const int my = blockIdx.x;
    const int b  = blockIdx.y;
    const int m0 = my * 64;

    const int tid = threadIdx.x;
    const int w = tid >> 6, lane = tid & 63;
    const int l15 = lane & 15, quad = lane >> 4;

    __shared__ unsigned short As[64 * 72];
    __shared__ unsigned short Bs[256 * 72];

    const unsigned short* Ag = Wpb + (size_t)m0 * 768;
    const unsigned short* Bg = OspT + (size_t)b * 256 * 768;

    f32x4 acc[4][4];
    #pragma unroll
    for (int mi = 0; mi < 4; mi++)
        #pragma unroll
        for (int ni = 0; ni < 4; ni++)
            acc[mi][ni] = (f32x4){0.f, 0.f, 0.f, 0.f};

    const int arow = tid >> 2, acol = (tid & 3) * 16;
    const int brow = tid >> 3, bcol = (tid & 7) * 8;

    for (int k0 = 0; k0 < 768; k0 += 64) {
        const short8 av0 = *(const short8*)&Ag[(size_t)arow * 768 + k0 + acol];
        const short8 av1 = *(const short8*)&Ag[(size_t)arow * 768 + k0 + acol + 8];
        short8 bv[8];
        #pragma unroll
        for (int p = 0; p < 8; p++)
            bv[p] = *(const short8*)&Bg[(size_t)(32 * p + brow) * 768 + k0 + bcol];
        __syncthreads();
        *(short8*)&As[arow * 72 + acol] = av0;
        *(short8*)&As[arow * 72 + acol + 8] = av1;
        #pragma unroll
        for (int p = 0; p < 8; p++)
            *(short8*)&Bs[(32 * p + brow) * 72 + bcol] = bv[p];
        __syncthreads();

        short8 af[4][2], bfr[4][2];
        #pragma unroll
        for (int mi = 0; mi < 4; mi++)
            #pragma unroll
            for (int kk = 0; kk < 2; kk++)
                af[mi][kk] = *(const short8*)&As[(16 * mi + l15) * 72 + 32 * kk + 8 * quad];
        #pragma unroll
        for (int ni = 0; ni < 4; ni++)
            #pragma unroll
            for (int kk = 0; kk < 2; kk++)
                bfr[ni][kk] = *(const short8*)&Bs[(64 * w + 16 * ni + l15) * 72 + 32 * kk + 8 * quad];
        #pragma unroll
        for (int kk = 0; kk < 2; kk++)
            #pragma unroll
            for (int mi = 0; mi < 4; mi++)
                #pragma unroll
                for (int ni = 0; ni < 4; ni++)
                    acc[mi][ni] = __builtin_amdgcn_mfma_f32_16x16x32_bf16(af[mi][kk], bfr[ni][kk], acc[mi][ni], 0, 0, 0);
    }

    const float kMix = 1.3130643285972254f; // 1/sqrt(0.58)
    #pragma unroll
    for (int mi = 0; mi < 4; mi++)
        #pragma unroll
        for (int r = 0; r < 4; r++) {
            const int m = m0 + 16 * mi + 4 * quad + r;
            const size_t rowb = (size_t)b * 196608 + (size_t)m * 256;
            #pragma unroll
            for (int ni = 0; ni < 4; ni++) {
                const int n = 64 * w + 16 * ni + l15;
                Out[rowb + n] = (0.7f * X[rowb + n] + 0.3f * acc[mi][ni][r]) * kMix;
            }
        }
}

// ---------------------------------------------------------------------------
extern "C" void kernel_launch(void* const* d_in, const int* in_sizes, int n_in,
                              void* d_out, int out_size, void* d_ws, size_t ws_size,
                              hipStream_t stream) {
    const float* x     = (const float*)d_in[0];
    const float* wqkv  = (const float*)d_in[1];
    const float* wproj = (const float*)d_in[2];
    float* out = (float*)d_out;

    // workspace layout (~55 MB). OspT aliases XbT (dead after qkv_mfma).
    char* ws = (char*)d_ws;
    unsigned short* Wqb  = (unsigned short*)(ws + 0);          //  3,538,944 B
    unsigned short* Wpb  = (unsigned short*)(ws + 3538944);    //  1,179,648 B
    unsigned short* XbT  = (unsigned short*)(ws + 4718592);    // 12,582,912 B
    unsigned short* OspT = XbT;                                // alias
    bf16*  Q   = (bf16*)(ws + 17301504);                       // 12,582,912 B
    bf16*  K   = (bf16*)(ws + 29884416);                       // 12,582,912 B
    bf16*  Vt  = (bf16*)(ws + 42467328);                       // 12,582,912 B -> 55,050,240

    rownorm_cast_kernel<<<3072, 256, 0, stream>>>(wqkv, wproj, Wqb, Wpb);
    cast_x_kernel<<<dim3(12, 32), 256, 0, stream>>>(x, XbT);
    qkv_mfma_kernel<<<dim3(36, 32), 256, 0, stream>>>(Wqb, XbT, Q, K, Vt);
    attn_mfma_kernel<<<dim3(32, 12, 2), 256, 0, stream>>>(Q, K, Vt, OspT);
    proj_mfma_kernel<<<dim3(12, 32), 256, 0, stream>>>(Wpb, OspT, x, out);
}

// Round 14
// 255.367 us; speedup vs baseline: 2.8294x; 1.0234x over previous
//
#include <hip/hip_runtime.h>
#include <hip/hip_bf16.h>
#include <math.h>

typedef __hip_bfloat16 bf16;
typedef __attribute__((ext_vector_type(8))) short short8;
typedef __attribute__((ext_vector_type(4))) float f32x4;

#define EPSV 0.0001f

__device__ __forceinline__ float bfbits2f(unsigned int u16) {
    return __uint_as_float(u16 << 16);
}
__device__ __forceinline__ unsigned short f2bf(float f) {  // RNE bf16 bits
    unsigned int u = __float_as_uint(f);
    u += 0x7fff + ((u >> 16) & 1);
    return (unsigned short)(u >> 16);
}
__device__ __forceinline__ unsigned int pkbf(float a, float b) {  // v_cvt_pk_bf16_f32
    __hip_bfloat162 h = __float22bfloat162_rn(make_float2(a, b));
    return *(unsigned int*)&h;
}
__device__ __forceinline__ float fast_exp2(float x) {      // v_exp_f32
    return __builtin_amdgcn_exp2f(x);
}

// ---------------------------------------------------------------------------
// Kernel 1: weight row-norm + cast to bf16 with scale folded in.
// ---------------------------------------------------------------------------
__global__ __launch_bounds__(256) void rownorm_cast_kernel(
    const float* __restrict__ w_qkv, const float* __restrict__ w_proj,
    unsigned short* __restrict__ Wqb, unsigned short* __restrict__ Wpb)
{
    const int row = blockIdx.x;
    const float* src;
    unsigned short* dst;
    if (row < 2304) { src = w_qkv + (size_t)row * 768;           dst = Wqb + (size_t)row * 768; }
    else            { src = w_proj + (size_t)(row - 2304) * 768; dst = Wpb + (size_t)(row - 2304) * 768; }

    const int tid = threadIdx.x;
    float v[3];
    float ss = 0.f;
    #pragma unroll
    for (int j = 0; j < 3; j++) {
        v[j] = src[tid + j * 256];
        ss += v[j] * v[j];
    }
    #pragma unroll
    for (int off = 32; off > 0; off >>= 1) ss += __shfl_down(ss, off, 64);
    __shared__ float wsum[4];
    if ((tid & 63) == 0) wsum[tid >> 6] = ss;
    __syncthreads();
    const float total = wsum[0] + wsum[1] + wsum[2] + wsum[3];
    const float scale = 1.0f / (EPSV * 27.712812921102035f + sqrtf(total)); // sqrt(768)
    #pragma unroll
    for (int j = 0; j < 3; j++) dst[tid + j * 256] = f2bf(v[j] * scale);
}

// ---------------------------------------------------------------------------
// Kernel 2: X [32][768][256] fp32 -> XbT [32][256][768] bf16 (transposed).
// ---------------------------------------------------------------------------
__global__ __launch_bounds__(256) void cast_x_kernel(
    const float* __restrict__ X, unsigned short* __restrict__ XbT)
{
    const int c0 = blockIdx.x * 64;
    const int b  = blockIdx.y;
    const int pos = threadIdx.x;
    const float* src = X + ((size_t)b * 768 + c0) * 256 + pos;
    unsigned short* dst = XbT + ((size_t)b * 256 + pos) * 768 + c0;
    #pragma unroll
    for (int cc = 0; cc < 8; cc++) {
        short8 t;
        #pragma unroll
        for (int j = 0; j < 8; j++)
            t[j] = (short)f2bf(src[(size_t)(cc * 8 + j) * 256]);
        *(short8*)&dst[cc * 8] = t;
    }
}

// ---------------------------------------------------------------------------
// Kernel 3: QKV GEMM (MFMA bf16), wide tile. Q pre-scaled by 0.125 (exact).
// ---------------------------------------------------------------------------
__global__ __launch_bounds__(256, 2) void qkv_mfma_kernel(
    const unsigned short* __restrict__ Wqb,  // [2304][768] bf16, scale folded
    const unsigned short* __restrict__ XbT,  // [32][256][768] bf16
    bf16* __restrict__ Q, bf16* __restrict__ K, bf16* __restrict__ Vt)
{
    const int g = blockIdx.x;            // 0..35 (= qkv*12 + head)
    const int b = blockIdx.y;            // 0..31 (= bs*16 + fr)
    const int bs = b >> 4, fr = b & 15;
    const int qkv = g / 12, head = g % 12;
    const int m0 = g * 64;

    const int tid = threadIdx.x;
    const int w = tid >> 6, lane = tid & 63;
    const int l15 = lane & 15, quad = lane >> 4;

    __shared__ unsigned short As[64 * 72];
    __shared__ unsigned short Bs[256 * 72];

    const unsigned short* Ag = Wqb + (size_t)m0 * 768;
    const unsigned short* Bg = XbT + (size_t)b * 256 * 768;

    f32x4 acc[4][4];   // [mi][ni]
    #pragma unroll
    for (int mi = 0; mi < 4; mi++)
        #pragma unroll
        for (int ni = 0; ni < 4; ni++)
            acc[mi][ni] = (f32x4){0.f, 0.f, 0.f, 0.f};

    const int arow = tid >> 2, acol = (tid & 3) * 16;
    const int brow = tid >> 3, bcol = (tid & 7) * 8;

    for (int k0 = 0; k0 < 768; k0 += 64) {
        const short8 av0 = *(const short8*)&Ag[(size_t)arow * 768 + k0 + acol];
        const short8 av1 = *(const short8*)&Ag[(size_t)arow * 768 + k0 + acol + 8];
        short8 bv[8];
        #pragma unroll
        for (int p = 0; p < 8; p++)
            bv[p] = *(const short8*)&Bg[(size_t)(32 * p + brow) * 768 + k0 + bcol];
        __syncthreads();
        *(short8*)&As[arow * 72 + acol] = av0;
        *(short8*)&As[arow * 72 + acol + 8] = av1;
        #pragma unroll
        for (int p = 0; p < 8; p++)
            *(short8*)&Bs[(32 * p + brow) * 72 + bcol] = bv[p];
        __syncthreads();

        short8 af[4][2], bfr[4][2];
        #pragma unroll
        for (int mi = 0; mi < 4; mi++)
            #pragma unroll
            for (int kk = 0; kk < 2; kk++)
                af[mi][kk] = *(const short8*)&As[(16 * mi + l15) * 72 + 32 * kk + 8 * quad];
        #pragma unroll
        for (int ni = 0; ni < 4; ni++)
            #pragma unroll
            for (int kk = 0; kk < 2; kk++)
                bfr[ni][kk] = *(const short8*)&Bs[(64 * w + 16 * ni + l15) * 72 + 32 * kk + 8 * quad];
        #pragma unroll
        for (int kk = 0; kk < 2; kk++)
            #pragma unroll
            for (int mi = 0; mi < 4; mi++)
                #pragma unroll
                for (int ni = 0; ni < 4; ni++)
                    acc[mi][ni] = __builtin_amdgcn_mfma_f32_16x16x32_bf16(af[mi][kk], bfr[ni][kk], acc[mi][ni], 0, 0, 0);
    }

    float inv[4];
    #pragma unroll
    for (int ni = 0; ni < 4; ni++) {
        float ssq = 0.f;
        #pragma unroll
        for (int mi = 0; mi < 4; mi++)
            #pragma unroll
            for (int r = 0; r < 4; r++)
                ssq = fmaf(acc[mi][ni][r], acc[mi][ni][r], ssq);
        ssq += __shfl_xor(ssq, 16, 64);
        ssq += __shfl_xor(ssq, 32, 64);
        inv[ni] = 1.0f / (EPSV + sqrtf(ssq) * 0.125f);
    }

    if (qkv == 2) {
        unsigned short* Vb = &Bs[w * 64 * 72];
        #pragma unroll
        for (int ni = 0; ni < 4; ni++)
            #pragma unroll
            for (int mi = 0; mi < 4; mi++) {
                uint2 d;
                d.x = pkbf(acc[mi][ni][0] * inv[ni], acc[mi][ni][1] * inv[ni]);
                d.y = pkbf(acc[mi][ni][2] * inv[ni], acc[mi][ni][3] * inv[ni]);
                *(uint2*)&Vb[(16 * ni + l15) * 72 + 16 * mi + 4 * quad] = d;
            }
        unsigned short* Vtu = (unsigned short*)Vt;
        const size_t cb = ((size_t)(bs * 12 + head) * 64);
        const int tok = fr * 256 + 64 * w + lane;
        #pragma unroll 8
        for (int ch = 0; ch < 64; ch++)
            Vtu[(cb + ch) * 4096 + tok] = Vb[lane * 72 + ch];
    } else {
        unsigned short* dst = (unsigned short*)((qkv == 0) ? Q : K);
        const float post = (qkv == 0) ? 0.125f : 1.0f;   // exact pow2 only
        #pragma unroll
        for (int ni = 0; ni < 4; ni++) {
            const int token = fr * 256 + 64 * w + 16 * ni + l15;
            const size_t base = (((size_t)(bs * 12 + head)) * 4096 + token) * 64;
            #pragma unroll
            for (int mi = 0; mi < 2; mi++) {
                unsigned int lo[2], hi[2];
                #pragma unroll
                for (int r = 0; r < 4; r++) {
                    const int j = 16 * mi + 4 * quad + r;
                    const float n1 = acc[mi][ni][r] * inv[ni];
                    const float n2 = acc[mi + 2][ni][r] * inv[ni];
                    const float ang = (float)fr * exp2f(-(float)j * 0.41524101186092029f);
                    float sn, cs;
                    __sincosf(ang, &sn, &cs);
                    const unsigned short o1 = f2bf((n1 * cs - n2 * sn) * post);
                    const unsigned short o2 = f2bf((n2 * cs + n1 * sn) * post);
                    if (r < 2) { if (r == 0) { lo[0] = o1; hi[0] = o2; } else { lo[0] |= (unsigned int)o1 << 16; hi[0] |= (unsigned int)o2 << 16; } }
                    else       { if (r == 2) { lo[1] = o1; hi[1] = o2; } else { lo[1] |= (unsigned int)o1 << 16; hi[1] |= (unsigned int)o2 << 16; } }
                }
                *(uint2*)&dst[base + 16 * mi + 4 * quad]      = make_uint2(lo[0], lo[1]);
                *(uint2*)&dst[base + 32 + 16 * mi + 4 * quad] = make_uint2(hi[0], hi[1]);
            }
        }
    }
}

// ---------------------------------------------------------------------------
// Kernel 4: MFMA flash attention, frame-paired, SPLIT-PHASE:
//  - S-phase split by KEYS: wave w computes S^T rows for keys 16w..16w+15,
//    for all 64 queries of both tiles. K fragments come DIRECTLY from global
//    (each K row read exactly once per block — removes the 4x LDS duplicate
//    kf reads and the whole Ks staging buffer: 112 -> 72 KB LDS per chunk).
//  - P -> block-shared Pw; barrier.
//  - PV-phase split by QUERIES (wave w owns q 16w..16w+15), vf from Vs.
//  - l accumulated in PV from P fragments (cross-wave-consistent).
// ---------------------------------------------------------------------------
__global__ __launch_bounds__(256, 3) void attn_mfma_kernel(
    const bf16* __restrict__ Qg, const bf16* __restrict__ Kg,
    const bf16* __restrict__ Vtg, unsigned short* __restrict__ OspT)
{
    const int px = blockIdx.x;                  // 0..31
    const int p = px >> 2, sub = px & 3;
    const int fa = p, fb = 15 - p;              // light / heavy frame
    const int head = blockIdx.y, bs = blockIdx.z;
    const int tid = threadIdx.x;
    const int w = tid >> 6, lane = tid & 63;
    const int l15 = lane & 15, quad = lane >> 4;
    const size_t hb = ((size_t)(bs * 12 + head)) * 4096 * 64;

    __shared__ unsigned short Vs[64 * 72];        //  9.2 KB
    __shared__ unsigned short Pw[2][64 * 72];     // 18.4 KB (block-shared)

    const unsigned short* Qu = (const unsigned short*)Qg;
    const unsigned short* Ku = (const unsigned short*)Kg;
    const unsigned short* Vu = (const unsigned short*)Vtg;

    // ALL 64 queries' B-fragments per wave (S-phase needs them all)
    short8 Qfa[4][2], Qfb[4][2];
    #pragma unroll
    for (int ni = 0; ni < 4; ni++) {
        const int qra = fa * 256 + sub * 64 + 16 * ni + l15;
        const int qrb = fb * 256 + sub * 64 + 16 * ni + l15;
        #pragma unroll
        for (int kk = 0; kk < 2; kk++) {
            Qfa[ni][kk] = *(const short8*)&Qu[hb + (size_t)qra * 64 + 32 * kk + 8 * quad];
            Qfb[ni][kk] = *(const short8*)&Qu[hb + (size_t)qrb * 64 + 32 * kk + 8 * quad];
        }
    }

    f32x4 Oa[4], Ob[4];
    #pragma unroll
    for (int c = 0; c < 4; c++) {
        Oa[c] = (f32x4){0.f, 0.f, 0.f, 0.f};
        Ob[c] = (f32x4){0.f, 0.f, 0.f, 0.f};
    }
    float la = 0.f, lb = 0.f;
    const f32x4 zf = (f32x4){0.f, 0.f, 0.f, 0.f};
    const float L2E = 1.4426950408889634f;
    const float C = 11.541560327111707f;          // 8 * log2(e)

    // V staging (64 ch rows x 64 keys), 4 threads/row
    const int stage_row = tid >> 2;
    const int stage_off = (tid & 3) * 16;
    const unsigned short* Vst = Vu + hb + (size_t)stage_row * 4096 + stage_off;
    // per-wave K fragment base: key row = t0 + 16w + l15
    const unsigned short* Klane = Ku + hb + (size_t)(16 * w + l15) * 64 + 8 * quad;

    // prefetch chunk 0 V
    short8 va = *(const short8*)&Vst[0];
    short8 vb = *(const short8*)&Vst[8];

    const int nka = (fa + 1) * 256;
    const int nkb = (fb + 1) * 256;
    for (int t0 = 0; t0 < nkb; t0 += 64) {
        __syncthreads();                          // (A) prior PV reads done
        // K fragments for this chunk straight from global (issued early so
        // the L2 latency overlaps the stage write + barrier below)
        const short8 kf0 = *(const short8*)&Klane[(size_t)t0 * 64];
        const short8 kf1 = *(const short8*)&Klane[(size_t)t0 * 64 + 32];
        *(short8*)&Vs[stage_row * 72 + stage_off] = va;
        *(short8*)&Vs[stage_row * 72 + stage_off + 8] = vb;
        __syncthreads();                          // (B) Vs visible

        // prefetch next chunk's V
        const int tn = (t0 + 64 < nkb) ? t0 + 64 : t0;
        va = *(const short8*)&Vst[tn];
        vb = *(const short8*)&Vst[tn + 8];

        const bool doA = (t0 < nka);              // block-uniform branch

        // S-phase: wave w -> keys 16w+4quad+r, all queries 16ni+l15
        {
            f32x4 St[4];
            #pragma unroll
            for (int ni = 0; ni < 4; ni++) {
                f32x4 s = __builtin_amdgcn_mfma_f32_16x16x32_bf16(kf0, Qfb[ni][0], zf, 0, 0, 0);
                St[ni] = __builtin_amdgcn_mfma_f32_16x16x32_bf16(kf1, Qfb[ni][1], s, 0, 0, 0);
            }
            #pragma unroll
            for (int ni = 0; ni < 4; ni++) {
                const f32x4 s = St[ni];
                uint2 d;
                d.x = pkbf(fast_exp2(fmaf(s[0], L2E, -C)), fast_exp2(fmaf(s[1], L2E, -C)));
                d.y = pkbf(fast_exp2(fmaf(s[2], L2E, -C)), fast_exp2(fmaf(s[3], L2E, -C)));
                *(uint2*)&Pw[1][(16 * ni + l15) * 72 + 16 * w + 4 * quad] = d;
            }
            if (doA) {
                #pragma unroll
                for (int ni = 0; ni < 4; ni++) {
                    f32x4 s = __builtin_amdgcn_mfma_f32_16x16x32_bf16(kf0, Qfa[ni][0], zf, 0, 0, 0);
                    St[ni] = __builtin_amdgcn_mfma_f32_16x16x32_bf16(kf1, Qfa[ni][1], s, 0, 0, 0);
                }
                #pragma unroll
                for (int ni = 0; ni < 4; ni++) {
                    const f32x4 s = St[ni];
                    uint2 d;
                    d.x = pkbf(fast_exp2(fmaf(s[0], L2E, -C)), fast_exp2(fmaf(s[1], L2E, -C)));
                    d.y = pkbf(fast_exp2(fmaf(s[2], L2E, -C)), fast_exp2(fmaf(s[3], L2E, -C)));
                    *(uint2*)&Pw[0][(16 * ni + l15) * 72 + 16 * w + 4 * quad] = d;
                }
            }
        }
        __syncthreads();                          // (C) Pw visible to all waves

        // PV-phase: wave w -> queries 16w+l15 (all keys of the chunk)
        short8 Pfb[2], Pfa[2];
        #pragma unroll
        for (int ks = 0; ks < 2; ks++)
            Pfb[ks] = *(const short8*)&Pw[1][(16 * w + l15) * 72 + 32 * ks + 8 * quad];
        if (doA) {
            #pragma unroll
            for (int ks = 0; ks < 2; ks++)
                Pfa[ks] = *(const short8*)&Pw[0][(16 * w + l15) * 72 + 32 * ks + 8 * quad];
        }
        // l accumulation from the P fragments (each lane: 16 distinct keys)
        #pragma unroll
        for (int ks = 0; ks < 2; ks++) {
            const unsigned int* ub = (const unsigned int*)&Pfb[ks];
            #pragma unroll
            for (int j = 0; j < 4; j++)
                lb += bfbits2f(ub[j] & 0xffffu) + bfbits2f(ub[j] >> 16);
        }
        if (doA) {
            #pragma unroll
            for (int ks = 0; ks < 2; ks++) {
                const unsigned int* ua = (const unsigned int*)&Pfa[ks];
                #pragma unroll
                for (int j = 0; j < 4; j++)
                    la += bfbits2f(ua[j] & 0xffffu) + bfbits2f(ua[j] >> 16);
            }
        }
        #pragma unroll
        for (int ci = 0; ci < 4; ci++) {
            const short8 vf0 = *(const short8*)&Vs[(16 * ci + l15) * 72 + 8 * quad];
            const short8 vf1 = *(const short8*)&Vs[(16 * ci + l15) * 72 + 32 + 8 * quad];
            Ob[ci] = __builtin_amdgcn_mfma_f32_16x16x32_bf16(Pfb[0], vf0, Ob[ci], 0, 0, 0);
            Ob[ci] = __builtin_amdgcn_mfma_f32_16x16x32_bf16(Pfb[1], vf1, Ob[ci], 0, 0, 0);
            if (doA) {
                Oa[ci] = __builtin_amdgcn_mfma_f32_16x16x32_bf16(Pfa[0], vf0, Oa[ci], 0, 0, 0);
                Oa[ci] = __builtin_amdgcn_mfma_f32_16x16x32_bf16(Pfa[1], vf1, Oa[ci], 0, 0, 0);
            }
        }
    }

    la += __shfl_xor(la, 16, 64);
    la += __shfl_xor(la, 32, 64);
    la = 1.0f / la;
    lb += __shfl_xor(lb, 16, 64);
    lb += __shfl_xor(lb, 32, 64);
    lb = 1.0f / lb;

    // epilogue for both query tiles (wave w owns queries 16w..16w+15)
    const size_t oba = ((size_t)(bs * 16 + fa)) * 196608;
    const size_t obb = ((size_t)(bs * 16 + fb)) * 196608;
    #pragma unroll
    for (int r = 0; r < 4; r++) {
        const float ia = __shfl(la, quad * 4 + r, 64);
        const float ib = __shfl(lb, quad * 4 + r, 64);
        const int pos = sub * 64 + w * 16 + 4 * quad + r;
        #pragma unroll
        for (int ci = 0; ci < 4; ci++) {
            const int chan = (16 * ci + l15) * 12 + head;
            OspT[oba + (size_t)pos * 768 + chan] = f2bf(Oa[ci][r] * ia);
            OspT[obb + (size_t)pos * 768 + chan] = f2bf(Ob[ci][r] * ib);
        }
    }
}

// ---------------------------------------------------------------------------
// Kernel 5: projection GEMM (MFMA bf16), wide tile, + residual mix epilogue.
// ---------------------------------------------------------------------------
__global__ __launch_bounds__(256, 2) void proj_mfma_kernel(
    const unsigned short* __restrict__ Wpb,   // [768][768] bf16, scale folded
    const unsigned short* __restrict__ OspT,  // [32][256][768] bf16
    const float* __restrict__ X,
    float* __restrict__ Out)
{
    const int my = blockIdx.x;
    const int b  = blockIdx.y;
    const int m0 = my * 64;

    const int tid = threadIdx.x;
    const int w = tid >> 6, lane = tid & 63;
    const int l15 = lane & 15, quad = lane >> 4;

    __shared__ unsigned short As[64 * 72];
    __shared__ unsigned short Bs[256 * 72];

    const unsigned short* Ag = Wpb + (size_t)m0 * 768;
    const unsigned short* Bg = OspT + (size_t)b * 256 * 768;

    f32x4 acc[4][4];
    #pragma unroll
    for (int mi = 0; mi < 4; mi++)
        #pragma unroll
        for (int ni = 0; ni < 4; ni++)
            acc[mi][ni] = (f32x4){0.f, 0.f, 0.f, 0.f};

    const int arow = tid >> 2, acol = (tid & 3) * 16;
    const int brow = tid >> 3, bcol = (tid & 7) * 8;

    for (int k0 = 0; k0 < 768; k0 += 64) {
        const short8 av0 = *(const short8*)&Ag[(size_t)arow * 768 + k0 + acol];
        const short8 av1 = *(const short8*)&Ag[(size_t)arow * 768 + k0 + acol + 8];
        short8 bv[8];
        #pragma unroll
        for (int p = 0; p < 8; p++)
            bv[p] = *(const short8*)&Bg[(size_t)(32 * p + brow) * 768 + k0 + bcol];
        __syncthreads();
        *(short8*)&As[arow * 72 + acol] = av0;
        *(short8*)&As[arow * 72 + acol + 8] = av1;
        #pragma unroll
        for (int p = 0; p < 8; p++)
            *(short8*)&Bs[(32 * p + brow) * 72 + bcol] = bv[p];
        __syncthreads();

        short8 af[4][2], bfr[4][2];
        #pragma unroll
        for (int mi = 0; mi < 4; mi++)
            #pragma unroll
            for (int kk = 0; kk < 2; kk++)
                af[mi][kk] = *(const short8*)&As[(16 * mi + l15) * 72 + 32 * kk + 8 * quad];
        #pragma unroll
        for (int ni = 0; ni < 4; ni++)
            #pragma unroll
            for (int kk = 0; kk < 2; kk++)
                bfr[ni][kk] = *(const short8*)&Bs[(64 * w + 16 * ni + l15) * 72 + 32 * kk + 8 * quad];
        #pragma unroll
        for (int kk = 0; kk < 2; kk++)
            #pragma unroll
            for (int mi = 0; mi < 4; mi++)
                #pragma unroll
                for (int ni = 0; ni < 4; ni++)
                    acc[mi][ni] = __builtin_amdgcn_mfma_f32_16x16x32_bf16(af[mi][kk], bfr[ni][kk], acc[mi][ni], 0, 0, 0);
    }

    const float kMix = 1.3130643285972254f; // 1/sqrt(0.58)
    #pragma unroll
    for (int mi = 0; mi < 4; mi++)
        #pragma unroll
        for (int r = 0; r < 4; r++) {
            const int m = m0 + 16 * mi + 4 * quad + r;
            const size_t rowb = (size_t)b * 196608 + (size_t)m * 256;
            #pragma unroll
            for (int ni = 0; ni < 4; ni++) {
                const int n = 64 * w + 16 * ni + l15;
                Out[rowb + n] = (0.7f * X[rowb + n] + 0.3f * acc[mi][ni][r]) * kMix;
            }
        }
}

// ---------------------------------------------------------------------------
extern "C" void kernel_launch(void* const* d_in, const int* in_sizes, int n_in,
                              void* d_out, int out_size, void* d_ws, size_t ws_size,
                              hipStream_t stream) {
    const float* x     = (const float*)d_in[0];
    const float* wqkv  = (const float*)d_in[1];
    const float* wproj = (const float*)d_in[2];
    float* out = (float*)d_out;

    // workspace layout (~55 MB). OspT aliases XbT (dead after qkv_mfma).
    char* ws = (char*)d_ws;
    unsigned short* Wqb  = (unsigned short*)(ws + 0);          //  3,538,944 B
    unsigned short* Wpb  = (unsigned short*)(ws + 3538944);    //  1,179,648 B
    unsigned short* XbT  = (unsigned short*)(ws + 4718592);    // 12,582,912 B
    unsigned short* OspT = XbT;                                // alias
    bf16*  Q   = (bf16*)(ws + 17301504);                       // 12,582,912 B
    bf16*  K   = (bf16*)(ws + 29884416);                       // 12,582,912 B
    bf16*  Vt  = (bf16*)(ws + 42467328);                       // 12,582,912 B -> 55,050,240

    rownorm_cast_kernel<<<3072, 256, 0, stream>>>(wqkv, wproj, Wqb, Wpb);
    cast_x_kernel<<<dim3(12, 32), 256, 0, stream>>>(x, XbT);
    qkv_mfma_kernel<<<dim3(36, 32), 256, 0, stream>>>(Wqb, XbT, Q, K, Vt);
    attn_mfma_kernel<<<dim3(32, 12, 2), 256, 0, stream>>>(Q, K, Vt, OspT);
    proj_mfma_kernel<<<dim3(12, 32), 256, 0, stream>>>(Wpb, OspT, x, out);
}